// Round 2
// baseline (2191.857 us; speedup 1.0000x reference)
//
#include <hip/hip_runtime.h>
#include <hip/hip_bf16.h>

// SABlock: 3D ViT block. B=4, C=768, D=8,H=14,W=14 -> N=1568 tokens.
// heads=12, head_dim=64, hidden=3072.
// Inputs may be bf16 OR fp32 (dataset policy ambiguous): detect at runtime via
// ln1_w (= ones): first u32 low half == 0x3F80 iff bf16. Everything internal
// is canonical bf16 (fp32 residual stream), MFMA 16x16x32 bf16 GEMMs.

using bf16 = __hip_bfloat16;
typedef __bf16 bf16x8 __attribute__((ext_vector_type(8)));
typedef float f32x4 __attribute__((ext_vector_type(4)));

#define NTOK 1568
#define CDIM 768
#define NH 12
#define HD 64
#define HID 3072
#define BN 6272   // 4*1568

static __device__ __forceinline__ float bf2f(bf16 x) { return __bfloat162float(x); }
static __device__ __forceinline__ bf16 f2bf(float x) { return __float2bfloat16(x); }
static __device__ __forceinline__ bool probe_bf16(const unsigned* p) {
  return ((*p) & 0xFFFFu) == 0x3F80u;
}

// ---------------- input ingest: src (bf16 or fp32 per probe) -> canonical bf16
__global__ __launch_bounds__(256) void ingest_kernel(
    const void* __restrict__ src, bf16* __restrict__ dst, int n,
    const unsigned* __restrict__ probe) {
  bool isbf = probe_bf16(probe);
  int i = blockIdx.x * 256 + threadIdx.x;
  if (i >= n) return;
  if (isbf) dst[i] = ((const bf16*)src)[i];
  else      dst[i] = f2bf(((const float*)src)[i]);
}

// ---------------- depthwise 3x3x3 conv + residual + bias -> t (fp32 [B,N,C])
__global__ __launch_bounds__(256) void conv_pe_kernel(
    const bf16* __restrict__ x, const bf16* __restrict__ pw,
    const bf16* __restrict__ pb, float* __restrict__ t) {
  int bc = blockIdx.x;            // b*768 + c
  int c = bc % CDIM;
  int b = bc / CDIM;
  __shared__ float xs[NTOK];
  __shared__ float wf[27];
  const bf16* xp = x + (size_t)bc * NTOK;
  for (int i = threadIdx.x; i < NTOK; i += 256) xs[i] = bf2f(xp[i]);
  if (threadIdx.x < 27) wf[threadIdx.x] = bf2f(pw[c * 27 + threadIdx.x]);
  float pbc = bf2f(pb[c]);
  __syncthreads();
  for (int n = threadIdx.x; n < NTOK; n += 256) {
    int d = n / 196;
    int r = n % 196;
    int h = r / 14;
    int w = r % 14;
    float acc = xs[n] + pbc;
    #pragma unroll
    for (int kd = -1; kd <= 1; kd++) {
      int dd = d + kd;
      if ((unsigned)dd >= 8u) continue;
      #pragma unroll
      for (int kh = -1; kh <= 1; kh++) {
        int hh = h + kh;
        if ((unsigned)hh >= 14u) continue;
        #pragma unroll
        for (int kw = -1; kw <= 1; kw++) {
          int ww = w + kw;
          if ((unsigned)ww >= 14u) continue;
          acc += wf[(kd + 1) * 9 + (kh + 1) * 3 + (kw + 1)] * xs[(dd * 14 + hh) * 14 + ww];
        }
      }
    }
    t[((size_t)b * NTOK + n) * CDIM + c] = acc;
  }
}

// ---------------- LayerNorm: t fp32 [BN,768] -> h bf16 (pure LDS tree reduce)
__global__ __launch_bounds__(256) void ln_kernel(
    const float* __restrict__ t, const bf16* __restrict__ w,
    const bf16* __restrict__ bia, bf16* __restrict__ h) {
  __shared__ float rs[256], rq[256];
  int m = blockIdx.x;
  int tid = threadIdx.x;
  const float* row = t + (size_t)m * CDIM;
  float s = 0.f, q = 0.f;
  for (int i = tid; i < CDIM; i += 256) {
    float v = row[i];
    s += v;
    q += v * v;
  }
  rs[tid] = s; rq[tid] = q;
  __syncthreads();
  for (int st = 128; st > 0; st >>= 1) {
    if (tid < st) { rs[tid] += rs[tid + st]; rq[tid] += rq[tid + st]; }
    __syncthreads();
  }
  float mu = rs[0] * (1.f / CDIM);
  float var = rq[0] * (1.f / CDIM) - mu * mu;
  float rstd = rsqrtf(fmaxf(var, 0.f) + 1e-5f);
  for (int i = tid; i < CDIM; i += 256) {
    float v = (row[i] - mu) * rstd * bf2f(w[i]) + bf2f(bia[i]);
    h[(size_t)m * CDIM + i] = f2bf(v);
  }
}

// ---------------- GEMM  C[M,Nout] = A[M,K] * W[Nout,K]^T  (+ fused epilogues)
// EPI 0: qkv scatter to [B,12,N,64] per tensor (q scaled 0.125, no bias)
// EPI 1: proj: resid[m*768+col] += acc + bias (fp32 in-place)
// EPI 2: fc1: obf = gelu(acc + bias)  bf16, ld 3072
// EPI 3: fc2: obf = resid + acc + bias  bf16, ld 768, with NaN canary
template <int EPI>
__global__ __launch_bounds__(256) void gemm_bt(
    const bf16* __restrict__ A, const bf16* __restrict__ W,
    const bf16* __restrict__ bias, float* __restrict__ resid,
    bf16* __restrict__ oq, bf16* __restrict__ okk, bf16* __restrict__ ov,
    bf16* __restrict__ obf, int K) {
  int tid = threadIdx.x;
  int w = tid >> 6;
  int lane = tid & 63;
  int quad = lane >> 4;
  int l16 = lane & 15;
  int m_base = blockIdx.x * 64 + w * 16;
  int n_base = blockIdx.y * 64;

  const bf16* ap = A + (size_t)(m_base + l16) * K + quad * 8;
  const bf16* bp0 = W + (size_t)(n_base + 0 + l16) * K + quad * 8;
  const bf16* bp1 = W + (size_t)(n_base + 16 + l16) * K + quad * 8;
  const bf16* bp2 = W + (size_t)(n_base + 32 + l16) * K + quad * 8;
  const bf16* bp3 = W + (size_t)(n_base + 48 + l16) * K + quad * 8;

  f32x4 acc[4];
  #pragma unroll
  for (int j = 0; j < 4; j++) acc[j] = (f32x4){0.f, 0.f, 0.f, 0.f};

  for (int k0 = 0; k0 < K; k0 += 32) {
    bf16x8 a = *reinterpret_cast<const bf16x8*>(ap + k0);
    bf16x8 b0 = *reinterpret_cast<const bf16x8*>(bp0 + k0);
    bf16x8 b1 = *reinterpret_cast<const bf16x8*>(bp1 + k0);
    bf16x8 b2 = *reinterpret_cast<const bf16x8*>(bp2 + k0);
    bf16x8 b3 = *reinterpret_cast<const bf16x8*>(bp3 + k0);
    acc[0] = __builtin_amdgcn_mfma_f32_16x16x32_bf16(a, b0, acc[0], 0, 0, 0);
    acc[1] = __builtin_amdgcn_mfma_f32_16x16x32_bf16(a, b1, acc[1], 0, 0, 0);
    acc[2] = __builtin_amdgcn_mfma_f32_16x16x32_bf16(a, b2, acc[2], 0, 0, 0);
    acc[3] = __builtin_amdgcn_mfma_f32_16x16x32_bf16(a, b3, acc[3], 0, 0, 0);
  }

  #pragma unroll
  for (int j = 0; j < 4; j++) {
    int col = n_base + j * 16 + l16;
    if (EPI == 0) {
      int col0 = n_base + j * 16;
      int i3 = col0 / CDIM;        // 0=q 1=k 2=v (16-col tile never spans)
      int rem = col0 % CDIM;
      int head = rem >> 6;
      int dd = (rem & 63) + l16;
      bf16* dst = (i3 == 0) ? oq : (i3 == 1) ? okk : ov;
      float scale = (i3 == 0) ? 0.125f : 1.0f;
      #pragma unroll
      for (int reg = 0; reg < 4; reg++) {
        int m = m_base + quad * 4 + reg;
        int b = m / NTOK;
        int n = m % NTOK;
        dst[((size_t)(b * NH + head) * NTOK + n) * HD + dd] = f2bf(acc[j][reg] * scale);
      }
    } else if (EPI == 1) {
      float bb = bf2f(bias[col]);
      #pragma unroll
      for (int reg = 0; reg < 4; reg++) {
        int m = m_base + quad * 4 + reg;
        size_t idx = (size_t)m * CDIM + col;
        resid[idx] = resid[idx] + acc[j][reg] + bb;
      }
    } else if (EPI == 2) {
      float bb = bf2f(bias[col]);
      #pragma unroll
      for (int reg = 0; reg < 4; reg++) {
        int m = m_base + quad * 4 + reg;
        float xg = acc[j][reg] + bb;
        float ge = 0.5f * xg * (1.0f + erff(xg * 0.70710678118f));
        obf[(size_t)m * HID + col] = f2bf(ge);
      }
    } else {
      float bb = bf2f(bias[col]);
      #pragma unroll
      for (int reg = 0; reg < 4; reg++) {
        int m = m_base + quad * 4 + reg;
        size_t idx = (size_t)m * CDIM + col;
        float val = resid[idx] + acc[j][reg] + bb;
        if (!(fabsf(val) < 1e30f)) val = 1000.0f;   // NaN/inf canary
        obf[idx] = f2bf(val);
      }
    }
  }
}

// ---------------- attention: 8 query rows per block, scores in LDS,
// pure-LDS tree reductions for softmax.
__global__ __launch_bounds__(256) void attn_kernel(
    const bf16* __restrict__ q, const bf16* __restrict__ k,
    const bf16* __restrict__ v, bf16* __restrict__ o) {
  int blk = blockIdx.x;
  int bh = blk / 196;          // b*12 + head
  int n0 = (blk % 196) * 8;
  int b = bh / NH;
  int head = bh % NH;
  int tid = threadIdx.x;

  __shared__ float qs[8][64];
  __shared__ float s[8][NTOK];
  __shared__ float op[4][8][64];
  __shared__ float red[256];
  __shared__ float rowinv[8];

  const size_t base = (size_t)bh * NTOK * HD;
  for (int i = tid; i < 512; i += 256) {
    int r = i >> 6, d2 = i & 63;
    qs[r][d2] = bf2f(q[base + (size_t)(n0 + r) * HD + d2]);  // q pre-scaled 0.125
  }
  __syncthreads();

  // phase 1: scores (scalar, conservative)
  for (int m = tid; m < NTOK; m += 256) {
    const bf16* kp = k + base + (size_t)m * HD;
    float acc[8] = {0.f, 0.f, 0.f, 0.f, 0.f, 0.f, 0.f, 0.f};
    for (int d = 0; d < HD; d++) {
      float kv = bf2f(kp[d]);
      #pragma unroll
      for (int r = 0; r < 8; r++) acc[r] += qs[r][d] * kv;
    }
    #pragma unroll
    for (int r = 0; r < 8; r++) s[r][m] = acc[r];
  }
  __syncthreads();

  // phase 2: softmax per row (exp stored unnormalized; inverse sum saved)
  for (int r = 0; r < 8; r++) {
    float lm = -1e30f;
    for (int m = tid; m < NTOK; m += 256) lm = fmaxf(lm, s[r][m]);
    red[tid] = lm;
    __syncthreads();
    for (int st = 128; st > 0; st >>= 1) {
      if (tid < st) red[tid] = fmaxf(red[tid], red[tid + st]);
      __syncthreads();
    }
    float mx = red[0];
    __syncthreads();
    float ls = 0.f;
    for (int m = tid; m < NTOK; m += 256) {
      float e = expf(s[r][m] - mx);
      s[r][m] = e;
      ls += e;
    }
    red[tid] = ls;
    __syncthreads();
    for (int st = 128; st > 0; st >>= 1) {
      if (tid < st) red[tid] += red[tid + st];
      __syncthreads();
    }
    if (tid == 0) rowinv[r] = 1.f / red[0];
    __syncthreads();
  }

  // phase 3: o = P V   (4 wave-strips over m, partials in LDS)
  {
    int d2 = tid & 63;
    int rq = tid >> 6;
    float acc[8] = {0.f, 0.f, 0.f, 0.f, 0.f, 0.f, 0.f, 0.f};
    int m0 = rq * 392, m1 = m0 + 392;
    for (int m = m0; m < m1; m++) {
      float vv = bf2f(v[base + (size_t)m * HD + d2]);
      #pragma unroll
      for (int r = 0; r < 8; r++) acc[r] += s[r][m] * vv;
    }
    #pragma unroll
    for (int r = 0; r < 8; r++) op[rq][r][d2] = acc[r];
  }
  __syncthreads();
  for (int i = tid; i < 512; i += 256) {
    int r = i >> 6, d2 = i & 63;
    float val = (op[0][r][d2] + op[1][r][d2] + op[2][r][d2] + op[3][r][d2]) * rowinv[r];
    o[((size_t)(b * NTOK + n0 + r)) * CDIM + head * HD + d2] = f2bf(val);
  }
}

// ---------------- t3 bf16 [B,N,C] -> out [B,C,N], dtype per probe
__global__ __launch_bounds__(256) void out_transpose(
    const bf16* __restrict__ t3, bf16* __restrict__ ob, float* __restrict__ of,
    const unsigned* __restrict__ probe) {
  bool isbf = probe_bf16(probe);
  __shared__ float tile[32][33];
  int c0 = blockIdx.x * 32;
  int n0 = blockIdx.y * 32;
  int b = blockIdx.z;
  int tx = threadIdx.x & 31;
  int ty = threadIdx.x >> 5;
  for (int yy = ty; yy < 32; yy += 8)
    tile[yy][tx] = bf2f(t3[((size_t)b * NTOK + n0 + yy) * CDIM + c0 + tx]);
  __syncthreads();
  for (int yy = ty; yy < 32; yy += 8) {
    size_t oi = ((size_t)b * CDIM + c0 + yy) * NTOK + n0 + tx;
    float vv = tile[tx][yy];
    if (isbf) ob[oi] = f2bf(vv);
    else      of[oi] = vv;
  }
}

extern "C" void kernel_launch(void* const* d_in, const int* in_sizes, int n_in,
                              void* d_out, int out_size, void* d_ws, size_t ws_size,
                              hipStream_t stream) {
  const unsigned* probe = (const unsigned*)d_in[3];   // ln1_w = ones

  char* ws = (char*)d_ws;
  size_t cur = 0;
  auto alloc = [&](size_t bytes) -> char* {
    char* p = ws + cur;
    cur = (cur + bytes + 511) & ~(size_t)511;
    return p;
  };

  // canonical bf16 copies of all 14 inputs
  bf16* canon[14];
  for (int i = 0; i < 14; i++) canon[i] = (bf16*)alloc((size_t)in_sizes[i] * 2);

  float* t  = (float*)alloc((size_t)BN * CDIM * 4);       // fp32 residual stream
  bf16*  R1 = (bf16*)alloc((size_t)BN * CDIM * 2);        // h / o / h2 / t3
  bf16*  R2 = (bf16*)alloc((size_t)BN * HID * 2);         // q,k,v then g
  bf16* q  = R2;
  bf16* kk = R2 + (size_t)BN * CDIM;
  bf16* v  = R2 + (size_t)2 * BN * CDIM;
  bf16* g  = R2;
  (void)ws_size;

  // 0) ingest all inputs to canonical bf16
  for (int i = 0; i < 14; i++) {
    int n = in_sizes[i];
    ingest_kernel<<<(n + 255) / 256, 256, 0, stream>>>(d_in[i], canon[i], n, probe);
  }
  const bf16 *xc = canon[0], *pos_w = canon[1], *pos_b = canon[2],
             *ln1_w = canon[3], *ln1_b = canon[4], *qkv_w = canon[5],
             *proj_w = canon[6], *proj_b = canon[7], *ln2_w = canon[8],
             *ln2_b = canon[9], *fc1_w = canon[10], *fc1_b = canon[11],
             *fc2_w = canon[12], *fc2_b = canon[13];

  // 1) conv positional embedding + residual + bias -> t
  conv_pe_kernel<<<4 * CDIM, 256, 0, stream>>>(xc, pos_w, pos_b, t);
  // 2) LN1 -> R1 (h)
  ln_kernel<<<BN, 256, 0, stream>>>(t, ln1_w, ln1_b, R1);
  // 3) qkv GEMM -> q,k,v (R2)
  gemm_bt<0><<<dim3(BN / 64, 2304 / 64), 256, 0, stream>>>(
      R1, qkv_w, nullptr, nullptr, q, kk, v, nullptr, CDIM);
  // 4) attention -> R1 (o)
  attn_kernel<<<4 * NH * (NTOK / 8), 256, 0, stream>>>(q, kk, v, R1);
  // 5) proj GEMM: t += o@proj^T + b  (in place fp32)
  gemm_bt<1><<<dim3(BN / 64, CDIM / 64), 256, 0, stream>>>(
      R1, proj_w, proj_b, t, nullptr, nullptr, nullptr, nullptr, CDIM);
  // 6) LN2 -> R1 (h2)
  ln_kernel<<<BN, 256, 0, stream>>>(t, ln2_w, ln2_b, R1);
  // 7) fc1 + gelu -> g (R2; q/k/v dead)
  gemm_bt<2><<<dim3(BN / 64, HID / 64), 256, 0, stream>>>(
      R1, fc1_w, fc1_b, nullptr, nullptr, nullptr, nullptr, g, CDIM);
  // 8) fc2 + residual -> R1 (t3, bf16; h2 dead)
  gemm_bt<3><<<dim3(BN / 64, CDIM / 64), 256, 0, stream>>>(
      g, fc2_w, fc2_b, t, nullptr, nullptr, nullptr, R1, HID);
  // 9) transpose to [B,C,N], output dtype per probe
  out_transpose<<<dim3(CDIM / 32, NTOK / 32, 4), 256, 0, stream>>>(
      R1, (bf16*)d_out, (float*)d_out, probe);
}

// Round 3
// 556.490 us; speedup vs baseline: 3.9387x; 3.9387x over previous
//
#include <hip/hip_runtime.h>
#include <hip/hip_bf16.h>

// SABlock: 3D ViT block. B=4, C=768, D=8,H=14,W=14 -> N=1568 tokens.
// heads=12, head_dim=64, hidden=3072.
// Runtime dtype probe (ln1_w == ones): low u16 of first word == 0x3F80 iff bf16.
// Internal: canonical bf16 tensors, fp32 residual stream, MFMA 16x16x32 bf16.

using bf16 = __hip_bfloat16;
typedef __bf16 bf16x8 __attribute__((ext_vector_type(8)));
typedef float f32x4 __attribute__((ext_vector_type(4)));

#define NTOK 1568
#define CDIM 768
#define NH 12
#define HD 64
#define HID 3072
#define BN 6272   // 4*1568

static __device__ __forceinline__ float bf2f(bf16 x) { return __bfloat162float(x); }
static __device__ __forceinline__ bf16 f2bf(float x) { return __float2bfloat16(x); }
static __device__ __forceinline__ unsigned short bfbits(float f) {
  bf16 h = __float2bfloat16(f);
  return *reinterpret_cast<unsigned short*>(&h);
}
static __device__ __forceinline__ bool probe_bf16(const unsigned* p) {
  return ((*p) & 0xFFFFu) == 0x3F80u;
}

// ---------------- fused ingest: all 14 inputs -> canonical bf16
struct IngestArgs {
  const void* src[14];
  bf16* dst[14];
  int off[15];
};
__global__ __launch_bounds__(256) void ingest_all(IngestArgs a, const unsigned* __restrict__ probe) {
  bool isbf = probe_bf16(probe);
  int i = blockIdx.x * 256 + threadIdx.x;
  if (i >= a.off[14]) return;
  int j = 0;
  #pragma unroll
  for (int s = 0; s < 13; s++) if (i >= a.off[s + 1]) j = s + 1;
  int li = i - a.off[j];
  if (isbf) a.dst[j][li] = ((const bf16*)a.src[j])[li];
  else      a.dst[j][li] = f2bf(((const float*)a.src[j])[li]);
}

// ---------------- depthwise 3x3x3 conv + residual + bias -> t (fp32 [B,N,C])
__global__ __launch_bounds__(256) void conv_pe_kernel(
    const bf16* __restrict__ x, const bf16* __restrict__ pw,
    const bf16* __restrict__ pb, float* __restrict__ t) {
  int bc = blockIdx.x;            // b*768 + c
  int c = bc % CDIM;
  int b = bc / CDIM;
  __shared__ float xs[NTOK];
  __shared__ float wf[27];
  const bf16* xp = x + (size_t)bc * NTOK;
  for (int i = threadIdx.x; i < NTOK; i += 256) xs[i] = bf2f(xp[i]);
  if (threadIdx.x < 27) wf[threadIdx.x] = bf2f(pw[c * 27 + threadIdx.x]);
  float pbc = bf2f(pb[c]);
  __syncthreads();
  for (int n = threadIdx.x; n < NTOK; n += 256) {
    int d = n / 196;
    int r = n % 196;
    int h = r / 14;
    int w = r % 14;
    float acc = xs[n] + pbc;
    #pragma unroll
    for (int kd = -1; kd <= 1; kd++) {
      int dd = d + kd;
      if ((unsigned)dd >= 8u) continue;
      #pragma unroll
      for (int kh = -1; kh <= 1; kh++) {
        int hh = h + kh;
        if ((unsigned)hh >= 14u) continue;
        #pragma unroll
        for (int kw = -1; kw <= 1; kw++) {
          int ww = w + kw;
          if ((unsigned)ww >= 14u) continue;
          acc += wf[(kd + 1) * 9 + (kh + 1) * 3 + (kw + 1)] * xs[(dd * 14 + hh) * 14 + ww];
        }
      }
    }
    t[((size_t)b * NTOK + n) * CDIM + c] = acc;
  }
}

// ---------------- LayerNorm: t fp32 [BN,768] -> h bf16
__global__ __launch_bounds__(256) void ln_kernel(
    const float* __restrict__ t, const bf16* __restrict__ w,
    const bf16* __restrict__ bia, bf16* __restrict__ h) {
  __shared__ float rs[256], rq[256];
  int m = blockIdx.x;
  int tid = threadIdx.x;
  const float* row = t + (size_t)m * CDIM;
  float s = 0.f, q = 0.f;
  for (int i = tid; i < CDIM; i += 256) {
    float v = row[i];
    s += v;
    q += v * v;
  }
  rs[tid] = s; rq[tid] = q;
  __syncthreads();
  for (int st = 128; st > 0; st >>= 1) {
    if (tid < st) { rs[tid] += rs[tid + st]; rq[tid] += rq[tid + st]; }
    __syncthreads();
  }
  float mu = rs[0] * (1.f / CDIM);
  float var = rq[0] * (1.f / CDIM) - mu * mu;
  float rstd = rsqrtf(fmaxf(var, 0.f) + 1e-5f);
  for (int i = tid; i < CDIM; i += 256) {
    float v = (row[i] - mu) * rstd * bf2f(w[i]) + bf2f(bia[i]);
    h[(size_t)m * CDIM + i] = f2bf(v);
  }
}

// ---------------- 128x128 LDS-staged GEMM  C = A[M,K] * W[N,K]^T + epilogues
// EPI 0: qkv scatter: q,k -> [B,12,N,64] (q*0.125), v -> transposed [B,12,64,N]
// EPI 1: proj: resid += acc + bias (fp32 in-place)
// EPI 2: fc1: obf = gelu(acc+bias), ld HID
// EPI 3: fc2: obf = resid + acc + bias (bf16), ld CDIM
#define LDA 40   // padded LDS row stride (elems) for 32-wide K tiles

template <int EPI>
__global__ __launch_bounds__(256) void gemm128(
    const bf16* __restrict__ A, const bf16* __restrict__ W,
    const bf16* __restrict__ bias, float* __restrict__ resid,
    bf16* __restrict__ oq, bf16* __restrict__ okk, bf16* __restrict__ ovt,
    bf16* __restrict__ obf, int K) {
  __shared__ __align__(16) bf16 As[128 * LDA];
  __shared__ __align__(16) bf16 Bs[128 * LDA];
  int tid = threadIdx.x;
  int w = tid >> 6, lane = tid & 63, quad = lane >> 4, l16 = lane & 15;
  int wr = w >> 1, wc = w & 1;
  int m0 = blockIdx.x * 128, n0 = blockIdx.y * 128;

  int r0 = tid >> 2;            // 0..63
  int c0 = (tid & 3) * 8;       // 0,8,16,24
  const bf16* gA0 = A + (size_t)(m0 + r0) * K + c0;
  const bf16* gA1 = A + (size_t)(m0 + 64 + r0) * K + c0;
  const bf16* gB0 = W + (size_t)(n0 + r0) * K + c0;
  const bf16* gB1 = W + (size_t)(n0 + 64 + r0) * K + c0;
  bf16* lA0 = As + r0 * LDA + c0;
  bf16* lA1 = As + (64 + r0) * LDA + c0;
  bf16* lB0 = Bs + r0 * LDA + c0;
  bf16* lB1 = Bs + (64 + r0) * LDA + c0;

  f32x4 acc[4][4];
  #pragma unroll
  for (int mi = 0; mi < 4; mi++)
    #pragma unroll
    for (int ni = 0; ni < 4; ni++) acc[mi][ni] = (f32x4){0.f, 0.f, 0.f, 0.f};

  for (int k0 = 0; k0 < K; k0 += 32) {
    *reinterpret_cast<bf16x8*>(lA0) = *reinterpret_cast<const bf16x8*>(gA0 + k0);
    *reinterpret_cast<bf16x8*>(lA1) = *reinterpret_cast<const bf16x8*>(gA1 + k0);
    *reinterpret_cast<bf16x8*>(lB0) = *reinterpret_cast<const bf16x8*>(gB0 + k0);
    *reinterpret_cast<bf16x8*>(lB1) = *reinterpret_cast<const bf16x8*>(gB1 + k0);
    __syncthreads();
    bf16x8 af[4], bfr[4];
    #pragma unroll
    for (int mi = 0; mi < 4; mi++)
      af[mi] = *reinterpret_cast<const bf16x8*>(As + (wr * 64 + mi * 16 + l16) * LDA + quad * 8);
    #pragma unroll
    for (int ni = 0; ni < 4; ni++)
      bfr[ni] = *reinterpret_cast<const bf16x8*>(Bs + (wc * 64 + ni * 16 + l16) * LDA + quad * 8);
    #pragma unroll
    for (int mi = 0; mi < 4; mi++)
      #pragma unroll
      for (int ni = 0; ni < 4; ni++)
        acc[mi][ni] = __builtin_amdgcn_mfma_f32_16x16x32_bf16(af[mi], bfr[ni], acc[mi][ni], 0, 0, 0);
    __syncthreads();
  }

  int mrow0 = m0 + wr * 64 + quad * 4;
  #pragma unroll
  for (int mi = 0; mi < 4; mi++) {
    #pragma unroll
    for (int ni = 0; ni < 4; ni++) {
      int col0 = n0 + wc * 64 + ni * 16;
      int col = col0 + l16;
      if (EPI == 0) {
        int i3 = col0 / CDIM;
        int rem = col0 % CDIM;
        int head = rem >> 6;
        int ddb = rem & 63;          // 0,16,32,48
        if (i3 == 2) {
          // v transposed: vt[((b*NH+head)*HD + dd) * NTOK + n], 4 regs = 4 consecutive n
          int m4 = mrow0 + mi * 16;
          int b = m4 / NTOK, n4 = m4 % NTOK;
          ushort4 pk;
          pk.x = bfbits(acc[mi][ni][0]);
          pk.y = bfbits(acc[mi][ni][1]);
          pk.z = bfbits(acc[mi][ni][2]);
          pk.w = bfbits(acc[mi][ni][3]);
          size_t idx = ((size_t)(b * NH + head) * HD + ddb + l16) * NTOK + n4;
          *reinterpret_cast<ushort4*>(ovt + idx) = pk;
        } else {
          bf16* dst = (i3 == 0) ? oq : okk;
          float scale = (i3 == 0) ? 0.125f : 1.0f;
          int dd = ddb + l16;
          #pragma unroll
          for (int reg = 0; reg < 4; reg++) {
            int m = mrow0 + mi * 16 + reg;
            int b = m / NTOK, n = m % NTOK;
            dst[((size_t)(b * NH + head) * NTOK + n) * HD + dd] = f2bf(acc[mi][ni][reg] * scale);
          }
        }
      } else if (EPI == 1) {
        float bb = bf2f(bias[col]);
        #pragma unroll
        for (int reg = 0; reg < 4; reg++) {
          int m = mrow0 + mi * 16 + reg;
          size_t idx = (size_t)m * CDIM + col;
          resid[idx] = resid[idx] + acc[mi][ni][reg] + bb;
        }
      } else if (EPI == 2) {
        float bb = bf2f(bias[col]);
        #pragma unroll
        for (int reg = 0; reg < 4; reg++) {
          int m = mrow0 + mi * 16 + reg;
          float xg = acc[mi][ni][reg] + bb;
          float ge = 0.5f * xg * (1.0f + erff(xg * 0.70710678118f));
          obf[(size_t)m * HID + col] = f2bf(ge);
        }
      } else {
        float bb = bf2f(bias[col]);
        #pragma unroll
        for (int reg = 0; reg < 4; reg++) {
          int m = mrow0 + mi * 16 + reg;
          size_t idx = (size_t)m * CDIM + col;
          obf[idx] = f2bf(resid[idx] + acc[mi][ni][reg] + bb);
        }
      }
    }
  }
}

// ---------------- flash attention, MFMA. Q-tile 64 rows (16/wave), KV-tile 64.
// q,k: [B,NH,N,64] (q pre-scaled 0.125); vt: [B,NH,64,N]; o: [B,N,768].
__global__ __launch_bounds__(256) void attn_mfma(
    const bf16* __restrict__ q, const bf16* __restrict__ k,
    const bf16* __restrict__ vt, bf16* __restrict__ o) {
  __shared__ __align__(16) bf16 Ks[64 * 72];
  __shared__ __align__(16) bf16 Vs[64 * 72];
  __shared__ __align__(16) bf16 Ps[4][16 * 72];
  int tid = threadIdx.x;
  int w = tid >> 6, lane = tid & 63, quad = lane >> 4, l16 = lane & 15;
  int qt = blockIdx.x;          // 0..24 (last tile half-valid)
  int bh = blockIdx.y;          // b*12+head
  int b = bh / NH, head = bh % NH;
  const size_t kbase = (size_t)bh * NTOK * HD;

  int qr = qt * 64 + w * 16 + l16;
  int qrc = min(qr, NTOK - 1);
  bf16x8 aq0 = *reinterpret_cast<const bf16x8*>(q + kbase + (size_t)qrc * HD + quad * 8);
  bf16x8 aq1 = *reinterpret_cast<const bf16x8*>(q + kbase + (size_t)qrc * HD + 32 + quad * 8);

  f32x4 oacc[4];
  #pragma unroll
  for (int di = 0; di < 4; di++) oacc[di] = (f32x4){0.f, 0.f, 0.f, 0.f};
  float mrow[4] = {-1e30f, -1e30f, -1e30f, -1e30f};
  float lrow[4] = {0.f, 0.f, 0.f, 0.f};

  int sr0 = tid >> 3;           // 0..31
  int sc0 = (tid & 7) * 8;      // 0..56
  const bf16* gK = k + kbase + (size_t)sr0 * HD + sc0;
  const bf16* gV = vt + ((size_t)bh * HD + sr0) * NTOK + sc0;
  bf16* pw = Ps[w];

  for (int t = 0; t < 25; t++) {
    int m0 = t * 64;
    __syncthreads();
    *reinterpret_cast<bf16x8*>(Ks + sr0 * 72 + sc0) =
        *reinterpret_cast<const bf16x8*>(gK + (size_t)m0 * HD);
    *reinterpret_cast<bf16x8*>(Ks + (sr0 + 32) * 72 + sc0) =
        *reinterpret_cast<const bf16x8*>(gK + (size_t)(m0 + 32) * HD);
    *reinterpret_cast<bf16x8*>(Vs + sr0 * 72 + sc0) =
        *reinterpret_cast<const bf16x8*>(gV + m0);
    *reinterpret_cast<bf16x8*>(Vs + (sr0 + 32) * 72 + sc0) =
        *reinterpret_cast<const bf16x8*>(gV + 32 * (size_t)NTOK + m0);
    __syncthreads();

    // QK^T: S[16 rows][64 cols]
    f32x4 s[4];
    #pragma unroll
    for (int ni = 0; ni < 4; ni++) {
      bf16x8 b0 = *reinterpret_cast<const bf16x8*>(Ks + (ni * 16 + l16) * 72 + quad * 8);
      bf16x8 b1 = *reinterpret_cast<const bf16x8*>(Ks + (ni * 16 + l16) * 72 + 32 + quad * 8);
      f32x4 z = (f32x4){0.f, 0.f, 0.f, 0.f};
      z = __builtin_amdgcn_mfma_f32_16x16x32_bf16(aq0, b0, z, 0, 0, 0);
      z = __builtin_amdgcn_mfma_f32_16x16x32_bf16(aq1, b1, z, 0, 0, 0);
      s[ni] = z;
    }
    if (t == 24) {   // mask cols >= NTOK
      #pragma unroll
      for (int ni = 0; ni < 4; ni++)
        if (m0 + ni * 16 + l16 >= NTOK)
          s[ni] = (f32x4){-1e30f, -1e30f, -1e30f, -1e30f};
    }

    // online softmax (rows = quad*4+reg; cols spread over 16 lanes of quad)
    float al[4];
    #pragma unroll
    for (int r = 0; r < 4; r++) {
      float tm = fmaxf(fmaxf(s[0][r], s[1][r]), fmaxf(s[2][r], s[3][r]));
      tm = fmaxf(tm, __shfl_xor(tm, 1));
      tm = fmaxf(tm, __shfl_xor(tm, 2));
      tm = fmaxf(tm, __shfl_xor(tm, 4));
      tm = fmaxf(tm, __shfl_xor(tm, 8));
      float mn = fmaxf(mrow[r], tm);
      al[r] = __expf(mrow[r] - mn);
      mrow[r] = mn;
      float p0 = __expf(s[0][r] - mn);
      float p1 = __expf(s[1][r] - mn);
      float p2 = __expf(s[2][r] - mn);
      float p3 = __expf(s[3][r] - mn);
      s[0][r] = p0; s[1][r] = p1; s[2][r] = p2; s[3][r] = p3;
      float rsum = p0 + p1 + p2 + p3;
      rsum += __shfl_xor(rsum, 1);
      rsum += __shfl_xor(rsum, 2);
      rsum += __shfl_xor(rsum, 4);
      rsum += __shfl_xor(rsum, 8);
      lrow[r] = lrow[r] * al[r] + rsum;
    }
    #pragma unroll
    for (int di = 0; di < 4; di++) {
      oacc[di][0] *= al[0]; oacc[di][1] *= al[1];
      oacc[di][2] *= al[2]; oacc[di][3] *= al[3];
    }

    // P: C-layout -> A-layout via per-wave LDS
    #pragma unroll
    for (int ni = 0; ni < 4; ni++)
      #pragma unroll
      for (int r = 0; r < 4; r++)
        pw[(quad * 4 + r) * 72 + ni * 16 + l16] = f2bf(s[ni][r]);
    bf16x8 ap0 = *reinterpret_cast<const bf16x8*>(pw + l16 * 72 + quad * 8);
    bf16x8 ap1 = *reinterpret_cast<const bf16x8*>(pw + l16 * 72 + 32 + quad * 8);

    // O += P @ V  (B from Vs = V^T tile)
    #pragma unroll
    for (int di = 0; di < 4; di++) {
      bf16x8 bv0 = *reinterpret_cast<const bf16x8*>(Vs + (di * 16 + l16) * 72 + quad * 8);
      bf16x8 bv1 = *reinterpret_cast<const bf16x8*>(Vs + (di * 16 + l16) * 72 + 32 + quad * 8);
      oacc[di] = __builtin_amdgcn_mfma_f32_16x16x32_bf16(ap0, bv0, oacc[di], 0, 0, 0);
      oacc[di] = __builtin_amdgcn_mfma_f32_16x16x32_bf16(ap1, bv1, oacc[di], 0, 0, 0);
    }
  }

  int orow0 = qt * 64 + w * 16 + quad * 4;
  #pragma unroll
  for (int r = 0; r < 4; r++) {
    int row = orow0 + r;
    if (row < NTOK) {
      float inv = 1.0f / lrow[r];
      size_t obase = ((size_t)b * NTOK + row) * CDIM + head * HD + l16;
      #pragma unroll
      for (int di = 0; di < 4; di++)
        o[obase + di * 16] = f2bf(oacc[di][r] * inv);
    }
  }
}

// ---------------- t3 bf16 [B,N,C] -> out [B,C,N], dtype per probe
__global__ __launch_bounds__(256) void out_transpose(
    const bf16* __restrict__ t3, bf16* __restrict__ ob, float* __restrict__ of,
    const unsigned* __restrict__ probe) {
  bool isbf = probe_bf16(probe);
  __shared__ float tile[32][33];
  int c0 = blockIdx.x * 32;
  int n0 = blockIdx.y * 32;
  int b = blockIdx.z;
  int tx = threadIdx.x & 31;
  int ty = threadIdx.x >> 5;
  for (int yy = ty; yy < 32; yy += 8)
    tile[yy][tx] = bf2f(t3[((size_t)b * NTOK + n0 + yy) * CDIM + c0 + tx]);
  __syncthreads();
  for (int yy = ty; yy < 32; yy += 8) {
    size_t oi = ((size_t)b * CDIM + c0 + yy) * NTOK + n0 + tx;
    float vv = tile[tx][yy];
    if (isbf) ob[oi] = f2bf(vv);
    else      of[oi] = vv;
  }
}

extern "C" void kernel_launch(void* const* d_in, const int* in_sizes, int n_in,
                              void* d_out, int out_size, void* d_ws, size_t ws_size,
                              hipStream_t stream) {
  const unsigned* probe = (const unsigned*)d_in[3];   // ln1_w = ones

  char* ws = (char*)d_ws;
  size_t cur = 0;
  auto alloc = [&](size_t bytes) -> char* {
    char* p = ws + cur;
    cur = (cur + bytes + 511) & ~(size_t)511;
    return p;
  };

  bf16* canon[14];
  IngestArgs ia;
  int tot = 0;
  for (int i = 0; i < 14; i++) {
    canon[i] = (bf16*)alloc((size_t)in_sizes[i] * 2);
    ia.src[i] = d_in[i];
    ia.dst[i] = canon[i];
    ia.off[i] = tot;
    tot += in_sizes[i];
  }
  ia.off[14] = tot;

  float* t  = (float*)alloc((size_t)BN * CDIM * 4);   // fp32 residual stream
  bf16*  R1 = (bf16*)alloc((size_t)BN * CDIM * 2);    // h / o / h2 / t3
  bf16*  R2 = (bf16*)alloc((size_t)BN * HID * 2);     // q,k,vt then g
  bf16* q  = R2;
  bf16* kk = R2 + (size_t)BN * CDIM;
  bf16* vt = R2 + (size_t)2 * BN * CDIM;
  bf16* g  = R2;
  (void)ws_size;

  // 0) ingest all inputs to canonical bf16 (single dispatch)
  ingest_all<<<(tot + 255) / 256, 256, 0, stream>>>(ia, probe);
  const bf16 *xc = canon[0], *pos_w = canon[1], *pos_b = canon[2],
             *ln1_w = canon[3], *ln1_b = canon[4], *qkv_w = canon[5],
             *proj_w = canon[6], *proj_b = canon[7], *ln2_w = canon[8],
             *ln2_b = canon[9], *fc1_w = canon[10], *fc1_b = canon[11],
             *fc2_w = canon[12], *fc2_b = canon[13];

  // 1) conv positional embedding + residual + bias -> t
  conv_pe_kernel<<<4 * CDIM, 256, 0, stream>>>(xc, pos_w, pos_b, t);
  // 2) LN1 -> R1
  ln_kernel<<<BN, 256, 0, stream>>>(t, ln1_w, ln1_b, R1);
  // 3) qkv GEMM -> q,k (row layout), vt (transposed)
  gemm128<0><<<dim3(BN / 128, 2304 / 128), 256, 0, stream>>>(
      R1, qkv_w, nullptr, nullptr, q, kk, vt, nullptr, CDIM);
  // 4) flash attention -> R1 (o)
  attn_mfma<<<dim3(25, 4 * NH), 256, 0, stream>>>(q, kk, vt, R1);
  // 5) proj GEMM: t += o@proj^T + b
  gemm128<1><<<dim3(BN / 128, CDIM / 128), 256, 0, stream>>>(
      R1, proj_w, proj_b, t, nullptr, nullptr, nullptr, nullptr, CDIM);
  // 6) LN2 -> R1
  ln_kernel<<<BN, 256, 0, stream>>>(t, ln2_w, ln2_b, R1);
  // 7) fc1 + gelu -> g (q/k/vt dead)
  gemm128<2><<<dim3(BN / 128, HID / 128), 256, 0, stream>>>(
      R1, fc1_w, fc1_b, nullptr, nullptr, nullptr, nullptr, g, CDIM);
  // 8) fc2 + residual -> R1 (bf16 t3)
  gemm128<3><<<dim3(BN / 128, CDIM / 128), 256, 0, stream>>>(
      g, fc2_w, fc2_b, t, nullptr, nullptr, nullptr, R1, HID);
  // 9) transpose to [B,C,N], output dtype per probe
  out_transpose<<<dim3(CDIM / 32, NTOK / 32, 4), 256, 0, stream>>>(
      R1, (bf16*)d_out, (float*)d_out, probe);
}